// Round 1
// baseline (376.053 us; speedup 1.0000x reference)
//
#include <hip/hip_runtime.h>
#include <cstdint>

#define DM 1024
#define NH 16
#define HDIM 64
#define SEQ 2048
#define NB 2

typedef unsigned short u16;
typedef __attribute__((ext_vector_type(8))) short bf16x8;
typedef __attribute__((ext_vector_type(4))) float f32x4;
typedef __attribute__((ext_vector_type(16))) float f32x16;
typedef __attribute__((ext_vector_type(4))) unsigned short u16x4;

__device__ __forceinline__ u16 f2bf(float f) {
  uint32_t x = __float_as_uint(f);
  x += 0x7fffu + ((x >> 16) & 1u);
  return (u16)(x >> 16);
}

// async global->LDS, 16B per lane. LDS dest = wave-uniform base + lane*16.
__device__ __forceinline__ void gload_lds16(const void* g, void* lds) {
  __builtin_amdgcn_global_load_lds(
      (const __attribute__((address_space(1))) unsigned int*)(uintptr_t)g,
      (__attribute__((address_space(3))) unsigned int*)(uint32_t)(uintptr_t)lds,
      16, 0, 0);
}

__global__ __launch_bounds__(256) void cvt_kernel(const float4* __restrict__ src,
                                                  u16x4* __restrict__ dst, int n4) {
  int i = blockIdx.x * 256 + threadIdx.x;
  if (i < n4) {
    float4 v = src[i];
    u16x4 o = {f2bf(v.x), f2bf(v.y), f2bf(v.z), f2bf(v.w)};
    dst[i] = o;
  }
}

// maskT[kv][q] = mask[q][kv]
__global__ __launch_bounds__(256) void tr_kernel(const float* __restrict__ src,
                                                 float* __restrict__ dst) {
  __shared__ float tile[32][33];
  const int bx = blockIdx.x * 32, by = blockIdx.y * 32;
  const int tx = threadIdx.x & 31;
  const int ty = threadIdx.x >> 5;  // 0..7
#pragma unroll
  for (int r = 0; r < 32; r += 8)
    tile[ty + r][tx] = src[(size_t)(by + ty + r) * SEQ + bx + tx];
  __syncthreads();
#pragma unroll
  for (int r = 0; r < 32; r += 8)
    dst[(size_t)(bx + ty + r) * SEQ + by + tx] = tile[tx][ty + r];
}

// C = X @ W^T + b for 3 projections (blockIdx.z). m97 structure: 128x128 tile,
// BK=32, global_load_lds width 16, 16x16x32 bf16 MFMA, 64x64 per wave.
// Epilogue: Q,K -> (B,H,S,64); V -> transposed (B,H,64,S).
__global__ __launch_bounds__(256) void proj_kernel(
    const u16* __restrict__ Xq, const u16* __restrict__ Xk, const u16* __restrict__ Xv,
    const u16* __restrict__ Wqp, const u16* __restrict__ Wkp, const u16* __restrict__ Wvp,
    const float* __restrict__ bqp, const float* __restrict__ bkp, const float* __restrict__ bvp,
    u16* __restrict__ Qp, u16* __restrict__ Kp, u16* __restrict__ Vt) {
  __shared__ __align__(16) u16 sA[128 * 32];
  __shared__ __align__(16) u16 sB[128 * 32];
  const int t = threadIdx.x;
  const int w = t >> 6, lane = t & 63, quad = lane >> 4, l16 = lane & 15;
  const int wr = w >> 1, wc = w & 1;
  const int m0 = blockIdx.y * 128, n0 = blockIdx.x * 128;
  const int mode = blockIdx.z;
  const u16* X = mode == 0 ? Xq : (mode == 1 ? Xk : Xv);
  const u16* W = mode == 0 ? Wqp : (mode == 1 ? Wkp : Wvp);
  const float* bias = mode == 0 ? bqp : (mode == 1 ? bkp : bvp);

  f32x4 acc[4][4] = {};
  const int srow = lane >> 2;        // 0..15 (row within 16-row chunk)
  const int scol = (lane & 3) * 16;  // byte offset within 64B row

  for (int k0 = 0; k0 < DM; k0 += 32) {
    __syncthreads();
#pragma unroll
    for (int j = 0; j < 2; ++j) {
      const int rbase = (w * 2 + j) * 16;
      gload_lds16((const char*)X + ((size_t)(m0 + rbase + srow) * DM + k0) * 2 + scol,
                  (char*)sA + rbase * 64);
      gload_lds16((const char*)W + ((size_t)(n0 + rbase + srow) * DM + k0) * 2 + scol,
                  (char*)sB + rbase * 64);
    }
    __syncthreads();
    bf16x8 af[4], bfr[4];
#pragma unroll
    for (int i = 0; i < 4; ++i)
      af[i] = *(const bf16x8*)&sA[(wr * 64 + i * 16 + l16) * 32 + quad * 8];
#pragma unroll
    for (int j = 0; j < 4; ++j)
      bfr[j] = *(const bf16x8*)&sB[(wc * 64 + j * 16 + l16) * 32 + quad * 8];
#pragma unroll
    for (int i = 0; i < 4; ++i)
#pragma unroll
      for (int j = 0; j < 4; ++j)
        acc[i][j] = __builtin_amdgcn_mfma_f32_16x16x32_bf16(af[i], bfr[j], acc[i][j], 0, 0, 0);
  }

  float bb[4];
#pragma unroll
  for (int j = 0; j < 4; ++j) bb[j] = bias[n0 + wc * 64 + j * 16 + l16];

#pragma unroll
  for (int i = 0; i < 4; ++i) {
    const int mbase = m0 + wr * 64 + i * 16 + quad * 4;  // multiple of 4; no b straddle
    const int bidx = mbase >> 11;
    const int s = mbase & 2047;
#pragma unroll
    for (int j = 0; j < 4; ++j) {
      const int n = n0 + wc * 64 + j * 16 + l16;
      const int h = n >> 6, hd = n & 63;
      if (mode == 2) {
        u16x4 pk = {f2bf(acc[i][j][0] + bb[j]), f2bf(acc[i][j][1] + bb[j]),
                    f2bf(acc[i][j][2] + bb[j]), f2bf(acc[i][j][3] + bb[j])};
        *(u16x4*)&Vt[((size_t)(bidx * NH + h) * HDIM + hd) * SEQ + s] = pk;
      } else {
        u16* dst = (mode == 0) ? Qp : Kp;
#pragma unroll
        for (int r = 0; r < 4; ++r)
          dst[((size_t)(bidx * NH + h) * SEQ + (s + r)) * HDIM + hd] =
              f2bf(acc[i][j][r] + bb[j]);
      }
    }
  }
}

// Flash attention. Block = 4 waves, 128 q-rows (32/wave). kv tiles of 64.
// Computes S^T = K·Q^T so softmax stats live per-lane (col=q), then P via LDS
// round-trip -> PV with transposed-V (A·B^T pattern). 32x32x16 bf16 MFMA.
__global__ __launch_bounds__(256) void attn_kernel(
    const u16* __restrict__ Qp, const u16* __restrict__ Kp,
    const u16* __restrict__ Vt, const float* __restrict__ maskT,
    float* __restrict__ out) {
  __shared__ __align__(16) u16 sK[64 * 64];
  __shared__ __align__(16) u16 sV[64 * 64];
  __shared__ __align__(16) u16 sP[4][32 * 72];  // per-wave, stride 72 (pad 8)
  __shared__ float sAux[4][32];
  const int t = threadIdx.x, w = t >> 6, lane = t & 63;
  const int l31 = lane & 31, hl = lane >> 5;
  const int h = blockIdx.x, qt = blockIdx.y, b = blockIdx.z;
  const int q0 = qt * 128 + w * 32;
  const int qg = q0 + l31;  // this lane's q column
  const u16* Qh = Qp + (size_t)(b * NH + h) * SEQ * HDIM;
  const u16* Kh = Kp + (size_t)(b * NH + h) * SEQ * HDIM;
  const u16* Vh = Vt + (size_t)(b * NH + h) * HDIM * SEQ;

  // Q fragments (B operand: n=q=lane&31, k=d) hoisted for the whole kv loop
  bf16x8 qf[4];
#pragma unroll
  for (int kt = 0; kt < 4; ++kt)
    qf[kt] = *(const bf16x8*)(Qh + (size_t)qg * HDIM + kt * 16 + hl * 8);

  f32x16 o0 = {}, o1 = {};
  float m_run = -1e30f, l_run = 0.f;

  for (int kv0 = 0; kv0 < SEQ; kv0 += 64) {
    __syncthreads();  // prev iteration done reading sK/sV
    // stage K tile (64 kv x 64 d) and V^T tile (64 hd x 64 s), XOR-swizzled 16B chunks
#pragma unroll
    for (int rr = 0; rr < 2; ++rr) {
      const int chunk = w * 128 + rr * 64 + lane;
      const int row = chunk >> 3;
      const int c = (chunk & 7) ^ (row & 7);
      gload_lds16((const char*)Kh + ((size_t)(kv0 + row) * HDIM) * 2 + c * 16,
                  (char*)sK + (w * 128 + rr * 64) * 16);
      gload_lds16((const char*)Vh + (size_t)row * SEQ * 2 + (size_t)kv0 * 2 + c * 16,
                  (char*)sV + (w * 128 + rr * 64) * 16);
    }
    __syncthreads();  // drains vmcnt (global_load_lds) per barrier semantics

    // S^T = K · Q^T : D[kv][q], col(lane&31)=q, rows=kv via regmap
    f32x16 st0 = {}, st1 = {};
#pragma unroll
    for (int kt = 0; kt < 4; ++kt) {
      const int cid = 2 * kt + hl;
      bf16x8 kf0 = *(const bf16x8*)&sK[(l31 * 8 + (cid ^ (l31 & 7))) * 8];
      st0 = __builtin_amdgcn_mfma_f32_32x32x16_bf16(kf0, qf[kt], st0, 0, 0, 0);
      const int r1 = 32 + l31;
      bf16x8 kf1 = *(const bf16x8*)&sK[(r1 * 8 + (cid ^ (r1 & 7))) * 8];
      st1 = __builtin_amdgcn_mfma_f32_32x32x16_bf16(kf1, qf[kt], st1, 0, 0, 0);
    }

    // scale + mask + online softmax (all stats per-lane in col space)
    float mn = m_run;
#pragma unroll
    for (int r = 0; r < 16; ++r) {
      const int rmap = (r & 3) + 8 * (r >> 2) + 4 * hl;
      const float mv0 = maskT[(size_t)(kv0 + rmap) * SEQ + qg];
      const float mv1 = maskT[(size_t)(kv0 + 32 + rmap) * SEQ + qg];
      const float s0 = fmaf(st0[r], 0.125f, mv0);
      const float s1 = fmaf(st1[r], 0.125f, mv1);
      st0[r] = s0;
      st1[r] = s1;
      mn = fmaxf(mn, fmaxf(s0, s1));
    }
    mn = fmaxf(mn, __shfl_xor(mn, 32));  // combine kv-halves (hl)
    const float alpha = exp2f((m_run - mn) * 1.44269504f);
    float ls = 0.f;
#pragma unroll
    for (int r = 0; r < 16; ++r) {
      const int rmap = (r & 3) + 8 * (r >> 2) + 4 * hl;
      const float p0 = exp2f((st0[r] - mn) * 1.44269504f);
      const float p1 = exp2f((st1[r] - mn) * 1.44269504f);
      ls += p0 + p1;
      sP[w][l31 * 72 + rmap] = f2bf(p0);
      sP[w][l31 * 72 + 32 + rmap] = f2bf(p1);
    }
    ls += __shfl_xor(ls, 32);
    l_run = l_run * alpha + ls;
    m_run = mn;

    // alpha (per q=lane) -> row space via per-wave LDS (wave-internal, in-order)
    sAux[w][l31] = alpha;
    f32x4 av[4];
#pragma unroll
    for (int g = 0; g < 4; ++g) av[g] = *(const f32x4*)&sAux[w][g * 8 + hl * 4];
#pragma unroll
    for (int r = 0; r < 16; ++r) {
      const float a = av[r >> 2][r & 3];
      o0[r] *= a;
      o1[r] *= a;
    }

    // O += P · V : A=P (m=q, k=kv) from sP, B=V^T rows (n=hd, k=kv) from sV
#pragma unroll
    for (int kt = 0; kt < 4; ++kt) {
      const bf16x8 pf = *(const bf16x8*)&sP[w][l31 * 72 + kt * 16 + hl * 8];
      const int cid = 2 * kt + hl;
      bf16x8 vf0 = *(const bf16x8*)&sV[(l31 * 8 + (cid ^ (l31 & 7))) * 8];
      o0 = __builtin_amdgcn_mfma_f32_32x32x16_bf16(pf, vf0, o0, 0, 0, 0);
      const int r1 = 32 + l31;
      bf16x8 vf1 = *(const bf16x8*)&sV[(r1 * 8 + (cid ^ (r1 & 7))) * 8];
      o1 = __builtin_amdgcn_mfma_f32_32x32x16_bf16(pf, vf1, o1, 0, 0, 0);
    }
  }

  // epilogue: divide by l (transposed to row space), write fp32 (B,S,D)
  sAux[w][l31] = l_run;
  f32x4 lv[4];
#pragma unroll
  for (int g = 0; g < 4; ++g) lv[g] = *(const f32x4*)&sAux[w][g * 8 + hl * 4];
#pragma unroll
  for (int r = 0; r < 16; ++r) {
    const int rmap = (r & 3) + 8 * (r >> 2) + 4 * hl;
    const float inv = 1.f / lv[r >> 2][r & 3];
    float* op = out + (size_t)(b * SEQ + q0 + rmap) * DM + h * HDIM;
    op[l31] = o0[r] * inv;
    op[32 + l31] = o1[r] * inv;
  }
}

extern "C" void kernel_launch(void* const* d_in, const int* in_sizes, int n_in,
                              void* d_out, int out_size, void* d_ws, size_t ws_size,
                              hipStream_t stream) {
  const float* q = (const float*)d_in[0];
  const float* k = (const float*)d_in[1];
  const float* v = (const float*)d_in[2];
  const float* mask = (const float*)d_in[3];
  const float* Wq = (const float*)d_in[4];
  const float* bq = (const float*)d_in[5];
  const float* Wk = (const float*)d_in[6];
  const float* bk = (const float*)d_in[7];
  const float* Wv = (const float*)d_in[8];
  const float* bv = (const float*)d_in[9];

  char* ws = (char*)d_ws;
  u16* q_bf = (u16*)(ws + 0);
  u16* k_bf = (u16*)(ws + 8388608);
  u16* v_bf = (u16*)(ws + 16777216);
  u16* wq_bf = (u16*)(ws + 25165824);
  u16* wk_bf = (u16*)(ws + 27262976);
  u16* wv_bf = (u16*)(ws + 29360128);
  u16* Qp = (u16*)(ws + 31457280);
  u16* Kp = (u16*)(ws + 39845888);
  u16* Vt = (u16*)(ws + 48234496);
  float* maskT = (float*)(ws + 56623104);  // ends at 73400320 bytes

  // fp32 -> bf16
  cvt_kernel<<<4096, 256, 0, stream>>>((const float4*)q, (u16x4*)q_bf, 1048576);
  cvt_kernel<<<4096, 256, 0, stream>>>((const float4*)k, (u16x4*)k_bf, 1048576);
  cvt_kernel<<<4096, 256, 0, stream>>>((const float4*)v, (u16x4*)v_bf, 1048576);
  cvt_kernel<<<1024, 256, 0, stream>>>((const float4*)Wq, (u16x4*)wq_bf, 262144);
  cvt_kernel<<<1024, 256, 0, stream>>>((const float4*)Wk, (u16x4*)wk_bf, 262144);
  cvt_kernel<<<1024, 256, 0, stream>>>((const float4*)Wv, (u16x4*)wv_bf, 262144);

  // mask transpose for coalesced col-space loads
  tr_kernel<<<dim3(64, 64), 256, 0, stream>>>(mask, maskT);

  // projections (z selects Q/K/V)
  proj_kernel<<<dim3(8, 32, 3), 256, 0, stream>>>(q_bf, k_bf, v_bf, wq_bf, wk_bf, wv_bf,
                                                  bq, bk, bv, Qp, Kp, Vt);

  // attention: h fastest for maskT L2 sharing
  attn_kernel<<<dim3(16, 16, 2), 256, 0, stream>>>(Qp, Kp, Vt, maskT, (float*)d_out);
}

// Round 2
// 288.877 us; speedup vs baseline: 1.3018x; 1.3018x over previous
//
#include <hip/hip_runtime.h>
#include <cstdint>

#define DM 1024
#define NH 16
#define HDIM 64
#define SEQ 2048
#define NB 2

typedef unsigned short u16;
typedef unsigned int u32;
typedef __attribute__((ext_vector_type(8))) short bf16x8;
typedef __attribute__((ext_vector_type(8))) unsigned short u16x8;
typedef __attribute__((ext_vector_type(4))) float f32x4;
typedef __attribute__((ext_vector_type(16))) float f32x16;
typedef __attribute__((ext_vector_type(4))) unsigned short u16x4;

__device__ __forceinline__ u16 f2bf(float f) {
  uint32_t x = __float_as_uint(f);
  x += 0x7fffu + ((x >> 16) & 1u);
  return (u16)(x >> 16);
}

__device__ __forceinline__ u32 pack_bf2(float a, float b) {
  return (u32)f2bf(a) | ((u32)f2bf(b) << 16);
}

// async global->LDS, 16B per lane. LDS dest = wave-uniform base + lane*16.
__device__ __forceinline__ void gload_lds16(const void* g, void* lds) {
  __builtin_amdgcn_global_load_lds(
      (const __attribute__((address_space(1))) unsigned int*)(uintptr_t)g,
      (__attribute__((address_space(3))) unsigned int*)(uint32_t)(uintptr_t)lds,
      16, 0, 0);
}

// Fused fp32->bf16 for q,k,v,Wq,Wk,Wv (single launch).
__global__ __launch_bounds__(256) void cvt_kernel(
    const float4* __restrict__ s0, const float4* __restrict__ s1, const float4* __restrict__ s2,
    const float4* __restrict__ s3, const float4* __restrict__ s4, const float4* __restrict__ s5,
    u16x4* __restrict__ d0, u16x4* __restrict__ d1, u16x4* __restrict__ d2,
    u16x4* __restrict__ d3, u16x4* __restrict__ d4, u16x4* __restrict__ d5) {
  int i = blockIdx.x * 256 + threadIdx.x;
  const float4* s;
  u16x4* d;
  int off;
  if (i < 3 * 1048576) {
    int seg = i >> 20;
    off = i & 1048575;
    s = seg == 0 ? s0 : (seg == 1 ? s1 : s2);
    d = seg == 0 ? d0 : (seg == 1 ? d1 : d2);
  } else {
    int j = i - 3 * 1048576;
    int seg = j >> 18;
    off = j & 262143;
    s = seg == 0 ? s3 : (seg == 1 ? s4 : s5);
    d = seg == 0 ? d3 : (seg == 1 ? d4 : d5);
  }
  float4 v = s[off];
  u16x4 o = {f2bf(v.x), f2bf(v.y), f2bf(v.z), f2bf(v.w)};
  d[off] = o;
}

// maskP[t][q][i] (bf16), i = hl*16 + r, value = mask[q][t*32 + rmap(r,hl)] * log2e
// where rmap = (r&3) + 8*(r>>2) + 4*hl  (MFMA 32x32 C-layout row order).
__global__ __launch_bounds__(256) void maskprep_kernel(const float* __restrict__ mask,
                                                       u16* __restrict__ maskP) {
  const int idx = blockIdx.x * 256 + threadIdx.x;  // 64 tiles * 2048 q
  const int tg = idx >> 11;
  const int q = idx & 2047;
  const float* src = mask + (size_t)q * SEQ + tg * 32;
  float buf[32];
#pragma unroll
  for (int j = 0; j < 8; ++j) *(float4*)&buf[4 * j] = *(const float4*)(src + 4 * j);
  u16 outv[32];
#pragma unroll
  for (int i = 0; i < 32; ++i) {
    const int hl = i >> 4, r = i & 15;
    const int kvl = (r & 3) + 8 * (r >> 2) + 4 * hl;
    outv[i] = f2bf(buf[kvl] * 1.44269504f);
  }
  u16* dst = maskP + (size_t)idx * 32;
#pragma unroll
  for (int j = 0; j < 4; ++j) *(u16x8*)(dst + 8 * j) = *(const u16x8*)&outv[8 * j];
}

// C = X @ W^T + b for 3 projections (blockIdx.z). m97 structure: 128x128 tile,
// BK=32, global_load_lds width 16, 16x16x32 bf16 MFMA, 64x64 per wave.
// Epilogue: Q (scaled by 0.125*log2e), K -> (B,H,S,64); V -> transposed (B,H,64,S).
__global__ __launch_bounds__(256) void proj_kernel(
    const u16* __restrict__ Xq, const u16* __restrict__ Xk, const u16* __restrict__ Xv,
    const u16* __restrict__ Wqp, const u16* __restrict__ Wkp, const u16* __restrict__ Wvp,
    const float* __restrict__ bqp, const float* __restrict__ bkp, const float* __restrict__ bvp,
    u16* __restrict__ Qp, u16* __restrict__ Kp, u16* __restrict__ Vt) {
  __shared__ __align__(16) u16 sA[128 * 32];
  __shared__ __align__(16) u16 sB[128 * 32];
  const int t = threadIdx.x;
  const int w = t >> 6, lane = t & 63, quad = lane >> 4, l16 = lane & 15;
  const int wr = w >> 1, wc = w & 1;
  const int m0 = blockIdx.y * 128, n0 = blockIdx.x * 128;
  const int mode = blockIdx.z;
  const u16* X = mode == 0 ? Xq : (mode == 1 ? Xk : Xv);
  const u16* W = mode == 0 ? Wqp : (mode == 1 ? Wkp : Wvp);
  const float* bias = mode == 0 ? bqp : (mode == 1 ? bkp : bvp);

  f32x4 acc[4][4] = {};
  const int srow = lane >> 2;
  const int scol = (lane & 3) * 16;

  for (int k0 = 0; k0 < DM; k0 += 32) {
    __syncthreads();
#pragma unroll
    for (int j = 0; j < 2; ++j) {
      const int rbase = (w * 2 + j) * 16;
      gload_lds16((const char*)X + ((size_t)(m0 + rbase + srow) * DM + k0) * 2 + scol,
                  (char*)sA + rbase * 64);
      gload_lds16((const char*)W + ((size_t)(n0 + rbase + srow) * DM + k0) * 2 + scol,
                  (char*)sB + rbase * 64);
    }
    __syncthreads();
    bf16x8 af[4], bfr[4];
#pragma unroll
    for (int i = 0; i < 4; ++i)
      af[i] = *(const bf16x8*)&sA[(wr * 64 + i * 16 + l16) * 32 + quad * 8];
#pragma unroll
    for (int j = 0; j < 4; ++j)
      bfr[j] = *(const bf16x8*)&sB[(wc * 64 + j * 16 + l16) * 32 + quad * 8];
#pragma unroll
    for (int i = 0; i < 4; ++i)
#pragma unroll
      for (int j = 0; j < 4; ++j)
        acc[i][j] = __builtin_amdgcn_mfma_f32_16x16x32_bf16(af[i], bfr[j], acc[i][j], 0, 0, 0);
  }

  float bb[4];
#pragma unroll
  for (int j = 0; j < 4; ++j) bb[j] = bias[n0 + wc * 64 + j * 16 + l16];
  const float scl = (mode == 0) ? 0.18033688011f : 1.0f;  // 0.125 * log2(e)

#pragma unroll
  for (int i = 0; i < 4; ++i) {
    const int mbase = m0 + wr * 64 + i * 16 + quad * 4;
    const int bidx = mbase >> 11;
    const int s = mbase & 2047;
#pragma unroll
    for (int j = 0; j < 4; ++j) {
      const int n = n0 + wc * 64 + j * 16 + l16;
      const int h = n >> 6, hd = n & 63;
      if (mode == 2) {
        u16x4 pk = {f2bf(acc[i][j][0] + bb[j]), f2bf(acc[i][j][1] + bb[j]),
                    f2bf(acc[i][j][2] + bb[j]), f2bf(acc[i][j][3] + bb[j])};
        *(u16x4*)&Vt[((size_t)(bidx * NH + h) * HDIM + hd) * SEQ + s] = pk;
      } else {
        u16* dst = (mode == 0) ? Qp : Kp;
#pragma unroll
        for (int r = 0; r < 4; ++r)
          dst[((size_t)(bidx * NH + h) * SEQ + (s + r)) * HDIM + hd] =
              f2bf((acc[i][j][r] + bb[j]) * scl);
      }
    }
  }
}

// Flash attention, barrier-free K-loop. Block = 64 q x 4 waves; wave w owns
// kv in [512w, 512w+512), tiles of 32. All operands loaded directly from
// global (L2-served). S^T = K·Q'^T (col=q) -> per-lane softmax stats;
// P C->B-operand relayout via half-wave shfl_xor(32); O^T = V^T·P^T so
// alpha/l apply per-lane. One LDS merge epilogue across waves.
__global__ __launch_bounds__(256, 3) void attn_kernel(
    const u16* __restrict__ Qp, const u16* __restrict__ Kp,
    const u16* __restrict__ Vt, const u16* __restrict__ maskP,
    float* __restrict__ out) {
  __shared__ float sO[4][32][65];
  __shared__ float sM[4][64];
  __shared__ float sL[4][64];
  const int t = threadIdx.x, w = t >> 6, lane = t & 63;
  const int l31 = lane & 31, hl = lane >> 5;
  const int h = blockIdx.x, qt = blockIdx.y, b = blockIdx.z;
  const int q0 = qt * 64;
  const u16* Qh = Qp + (size_t)(b * NH + h) * SEQ * HDIM;
  const u16* Kh = Kp + (size_t)(b * NH + h) * SEQ * HDIM;
  const u16* Vh = Vt + (size_t)(b * NH + h) * HDIM * SEQ;

  bf16x8 qf[2][4];
#pragma unroll
  for (int sub = 0; sub < 2; ++sub)
#pragma unroll
    for (int kt = 0; kt < 4; ++kt)
      qf[sub][kt] =
          *(const bf16x8*)(Qh + (size_t)(q0 + sub * 32 + l31) * HDIM + kt * 16 + hl * 8);

  f32x16 oacc[2][2] = {};
  float m_run[2] = {-1e30f, -1e30f};
  float l_run[2] = {0.f, 0.f};

  const int kvw = w * 512;
  for (int it = 0; it < 16; ++it) {
    const int kv0 = kvw + it * 32;
    const int tg = kv0 >> 5;
    bf16x8 kf[4];
#pragma unroll
    for (int kt = 0; kt < 4; ++kt)
      kf[kt] = *(const bf16x8*)(Kh + (size_t)(kv0 + l31) * HDIM + kt * 16 + hl * 8);
    bf16x8 vf[2][2];
#pragma unroll
    for (int half = 0; half < 2; ++half)
#pragma unroll
      for (int ks = 0; ks < 2; ++ks)
        vf[half][ks] =
            *(const bf16x8*)(Vh + (size_t)(half * 32 + l31) * SEQ + kv0 + ks * 16 + hl * 8);

    bf16x8 pfr[2][2];
#pragma unroll
    for (int sub = 0; sub < 2; ++sub) {
      const u16* mrow = maskP + ((size_t)tg * SEQ + (q0 + sub * 32 + l31)) * 32 + hl * 16;
      u16x8 mk0 = *(const u16x8*)(mrow);
      u16x8 mk1 = *(const u16x8*)(mrow + 8);
      f32x16 st;
#pragma unroll
      for (int r = 0; r < 8; ++r) st[r] = __uint_as_float((u32)mk0[r] << 16);
#pragma unroll
      for (int r = 0; r < 8; ++r) st[8 + r] = __uint_as_float((u32)mk1[r] << 16);
#pragma unroll
      for (int kt = 0; kt < 4; ++kt)
        st = __builtin_amdgcn_mfma_f32_32x32x16_bf16(kf[kt], qf[sub][kt], st, 0, 0, 0);

      float mn = st[0];
#pragma unroll
      for (int r = 1; r < 16; ++r) mn = fmaxf(mn, st[r]);
      mn = fmaxf(mn, __shfl_xor(mn, 32));
      const float m_new = fmaxf(m_run[sub], mn);
      const float alpha = __builtin_amdgcn_exp2f(m_run[sub] - m_new);
      m_run[sub] = m_new;
      float p[16];
      float ls = 0.f;
#pragma unroll
      for (int r = 0; r < 16; ++r) {
        p[r] = __builtin_amdgcn_exp2f(st[r] - m_new);
        ls += p[r];
      }
      ls += __shfl_xor(ls, 32);
      l_run[sub] = l_run[sub] * alpha + ls;
#pragma unroll
      for (int half = 0; half < 2; ++half)
#pragma unroll
        for (int r = 0; r < 16; ++r) oacc[half][sub][r] *= alpha;

      u32 pk[4][2];
#pragma unroll
      for (int g = 0; g < 4; ++g) {
        pk[g][0] = pack_bf2(p[4 * g + 0], p[4 * g + 1]);
        pk[g][1] = pack_bf2(p[4 * g + 2], p[4 * g + 3]);
      }
#pragma unroll
      for (int ks = 0; ks < 2; ++ks) {
        // send quad g = 2ks+(1-hl); receive partner's quad g = 2ks+hl
        u32 sa = hl ? pk[2 * ks][0] : pk[2 * ks + 1][0];
        u32 sb = hl ? pk[2 * ks][1] : pk[2 * ks + 1][1];
        u32 ra = __shfl_xor(sa, 32);
        u32 rb = __shfl_xor(sb, 32);
        u32 oa = hl ? pk[2 * ks + 1][0] : pk[2 * ks][0];
        u32 ob = hl ? pk[2 * ks + 1][1] : pk[2 * ks][1];
        union {
          u32 u[4];
          bf16x8 v;
        } f;
        f.u[0] = hl ? ra : oa;  // j0..3 from hl_src=0
        f.u[1] = hl ? rb : ob;
        f.u[2] = hl ? oa : ra;  // j4..7 from hl_src=1
        f.u[3] = hl ? ob : rb;
        pfr[sub][ks] = f.v;
      }
    }
#pragma unroll
    for (int half = 0; half < 2; ++half)
#pragma unroll
      for (int sub = 0; sub < 2; ++sub)
#pragma unroll
        for (int ks = 0; ks < 2; ++ks)
          oacc[half][sub] = __builtin_amdgcn_mfma_f32_32x32x16_bf16(
              vf[half][ks], pfr[sub][ks], oacc[half][sub], 0, 0, 0);
  }

  // cross-wave merge epilogue
  if (hl == 0) {
    sM[w][l31] = m_run[0];
    sM[w][32 + l31] = m_run[1];
    sL[w][l31] = l_run[0];
    sL[w][32 + l31] = l_run[1];
  }
  const int hd = t & 31, grp = t >> 5;
#pragma unroll
  for (int half = 0; half < 2; ++half) {
    __syncthreads();
#pragma unroll
    for (int sub = 0; sub < 2; ++sub)
#pragma unroll
      for (int r = 0; r < 16; ++r)
        sO[w][(r & 3) + 8 * (r >> 2) + 4 * hl][sub * 32 + l31] = oacc[half][sub][r];
    __syncthreads();
#pragma unroll
    for (int p8 = 0; p8 < 8; ++p8) {
      const int qi = grp * 8 + p8;
      float m0 = sM[0][qi], m1 = sM[1][qi], m2 = sM[2][qi], m3 = sM[3][qi];
      float mx = fmaxf(fmaxf(m0, m1), fmaxf(m2, m3));
      float c0 = __builtin_amdgcn_exp2f(m0 - mx);
      float c1 = __builtin_amdgcn_exp2f(m1 - mx);
      float c2 = __builtin_amdgcn_exp2f(m2 - mx);
      float c3 = __builtin_amdgcn_exp2f(m3 - mx);
      float lsum = sL[0][qi] * c0 + sL[1][qi] * c1 + sL[2][qi] * c2 + sL[3][qi] * c3;
      float val = c0 * sO[0][hd][qi] + c1 * sO[1][hd][qi] + c2 * sO[2][hd][qi] +
                  c3 * sO[3][hd][qi];
      out[(size_t)(b * SEQ + q0 + qi) * DM + h * HDIM + half * 32 + hd] = val / lsum;
    }
  }
}

extern "C" void kernel_launch(void* const* d_in, const int* in_sizes, int n_in,
                              void* d_out, int out_size, void* d_ws, size_t ws_size,
                              hipStream_t stream) {
  const float* q = (const float*)d_in[0];
  const float* k = (const float*)d_in[1];
  const float* v = (const float*)d_in[2];
  const float* mask = (const float*)d_in[3];
  const float* Wq = (const float*)d_in[4];
  const float* bq = (const float*)d_in[5];
  const float* Wk = (const float*)d_in[6];
  const float* bk = (const float*)d_in[7];
  const float* Wv = (const float*)d_in[8];
  const float* bv = (const float*)d_in[9];

  char* ws = (char*)d_ws;
  u16* q_bf = (u16*)(ws + 0);
  u16* k_bf = (u16*)(ws + 8388608);
  u16* v_bf = (u16*)(ws + 16777216);
  u16* wq_bf = (u16*)(ws + 25165824);
  u16* wk_bf = (u16*)(ws + 27262976);
  u16* wv_bf = (u16*)(ws + 29360128);
  u16* Qp = (u16*)(ws + 31457280);
  u16* Kp = (u16*)(ws + 39845888);
  u16* Vt = (u16*)(ws + 48234496);
  u16* maskP = (u16*)(ws + 56623104);  // 8 MB, ends at 65011712

  cvt_kernel<<<15360, 256, 0, stream>>>(
      (const float4*)q, (const float4*)k, (const float4*)v, (const float4*)Wq,
      (const float4*)Wk, (const float4*)Wv, (u16x4*)q_bf, (u16x4*)k_bf, (u16x4*)v_bf,
      (u16x4*)wq_bf, (u16x4*)wk_bf, (u16x4*)wv_bf);

  maskprep_kernel<<<512, 256, 0, stream>>>(mask, maskP);

  proj_kernel<<<dim3(8, 32, 3), 256, 0, stream>>>(q_bf, k_bf, v_bf, wq_bf, wk_bf, wv_bf,
                                                  bq, bk, bv, Qp, Kp, Vt);

  attn_kernel<<<dim3(16, 32, 2), 256, 0, stream>>>(Qp, Kp, Vt, maskP, (float*)d_out);
}